// Round 3
// baseline (118.739 us; speedup 1.0000x reference)
//
#include <hip/hip_runtime.h>

// CVXPolicy_Quadcopter: fused MLP (13->100 tanh ->12) + closed-form argmin via
// Lambert W. 1 batch element per thread (max TLP: ~7.6 waves/SIMD, whole grid
// resident). Weights pre-packed into d_ws by a setup kernel:
//   W1T: 100 rows x 16 floats  [k0..k12, b1, 0, 0]   (64B-aligned rows)
//   W2P: 100 rows x 8  floats  [w2[j][6..11], 0, 0]  (32B-aligned rows)
// so the j-loop reads weights as a handful of wide scalar (SMEM) loads.

constexpr int S = 12;   // z features
constexpr int H = 100;  // hidden

__device__ __forceinline__ float fast_rcp(float x) {
    return __builtin_amdgcn_rcpf(x);
}

// tanh(x) = 1 - 2/(1 + e^{2x});  stable at both tails (rcp(inf)=0)
__device__ __forceinline__ float fast_tanh(float x) {
    float e = __expf(2.0f * x);
    return fmaf(-2.0f, fast_rcp(1.0f + e), 1.0f);
}

__global__ __launch_bounds__(256) void pack_weights(
    const float* __restrict__ W1, const float* __restrict__ b1,
    const float* __restrict__ W2, float* __restrict__ ws)
{
    int idx = blockIdx.x * 256 + threadIdx.x;
    if (idx < 1600) {                       // W1T region: j = idx/16, slot = idx%16
        int j = idx >> 4, k = idx & 15;
        float v = 0.0f;
        if (k < 13)       v = W1[k * H + j];
        else if (k == 13) v = b1[j];
        ws[idx] = v;
    } else if (idx < 2400) {                // W2P region: j = r/8, slot = r%8
        int r = idx - 1600;
        int j = r >> 3, m = r & 7;
        ws[idx] = (m < 6) ? W2[j * S + 6 + m] : 0.0f;
    }
}

__global__ __launch_bounds__(256) void cvx_quad_kernel(
    const float* __restrict__ z, const float* __restrict__ t,
    const float* __restrict__ ws, const float* __restrict__ b2,
    float* __restrict__ out, int B)
{
    int i = blockIdx.x * 256 + threadIdx.x;
    if (i >= B) return;

    const float* W1T = ws;          // 100 x 16
    const float* W2P = ws + 1600;   // 100 x 8

    // Load input row: [t, z0..z11]
    float inp[S + 1];
    inp[0] = t[i];
    const float4* zr = reinterpret_cast<const float4*>(z) + (size_t)i * 3;
    float4 a0 = zr[0], a1 = zr[1], a2 = zr[2];
    inp[1]  = a0.x; inp[2]  = a0.y; inp[3]  = a0.z; inp[4]  = a0.w;
    inp[5]  = a1.x; inp[6]  = a1.y; inp[7]  = a1.z; inp[8]  = a1.w;
    inp[9]  = a2.x; inp[10] = a2.y; inp[11] = a2.z; inp[12] = a2.w;

    float p0 = b2[6], p1 = b2[7], p2 = b2[8];
    float p3 = b2[9], p4 = b2[10], p5 = b2[11];

    #pragma unroll 2
    for (int j = 0; j < H; ++j) {
        const float4* wr = reinterpret_cast<const float4*>(W1T + j * 16);
        float4 wa = wr[0], wb = wr[1], wc = wr[2], wd = wr[3];
        float acc = wd.y;                     // b1[j] folded into slot 13
        acc = fmaf(inp[0],  wa.x, acc);
        acc = fmaf(inp[1],  wa.y, acc);
        acc = fmaf(inp[2],  wa.z, acc);
        acc = fmaf(inp[3],  wa.w, acc);
        acc = fmaf(inp[4],  wb.x, acc);
        acc = fmaf(inp[5],  wb.y, acc);
        acc = fmaf(inp[6],  wb.z, acc);
        acc = fmaf(inp[7],  wb.w, acc);
        acc = fmaf(inp[8],  wc.x, acc);
        acc = fmaf(inp[9],  wc.y, acc);
        acc = fmaf(inp[10], wc.z, acc);
        acc = fmaf(inp[11], wc.w, acc);
        acc = fmaf(inp[12], wd.x, acc);

        float th = fast_tanh(acc);

        const float4* qr = reinterpret_cast<const float4*>(W2P + j * 8);
        float4 qa = qr[0], qb = qr[1];        // qb.z, qb.w are zero padding
        p0 = fmaf(th, qa.x, p0);
        p1 = fmaf(th, qa.y, p1);
        p2 = fmaf(th, qa.z, p2);
        p3 = fmaf(th, qa.w, p3);
        p4 = fmaf(th, qb.x, p4);
        p5 = fmaf(th, qb.y, p5);
    }

    float c0 = 2.0f * (p0 + p1 + p2);  // / MASS, MASS = 0.5
    float c1 = p3, c2 = p4, c3 = p5;
    float x = fmaf(c0, c0, fmaf(c1, c1, fmaf(c2, c2, c3 * c3)));

    // Lambert W: solve w e^w = x, Newton from w0 = log(1+x)
    float w = __logf(1.0f + x);
    #pragma unroll
    for (int it = 0; it < 6; ++it) {
        float ew  = __expf(w);
        float num = fmaf(w, ew, -x);        // w*e^w - x
        float den = fmaf(ew, w, ew);        // e^w * (w + 1)
        w = w - num * fast_rcp(den);
    }

    float sc = -__expf(-0.5f * w);
    float4 o;
    o.x = c0 * sc;
    o.y = c1 * sc;
    o.z = c2 * sc;
    o.w = c3 * sc;
    reinterpret_cast<float4*>(out)[i] = o;
}

extern "C" void kernel_launch(void* const* d_in, const int* in_sizes, int n_in,
                              void* d_out, int out_size, void* d_ws, size_t ws_size,
                              hipStream_t stream) {
    const float* z  = (const float*)d_in[0];
    const float* t  = (const float*)d_in[1];
    const float* W1 = (const float*)d_in[2];
    const float* b1 = (const float*)d_in[3];
    const float* W2 = (const float*)d_in[4];
    const float* b2 = (const float*)d_in[5];
    float* out = (float*)d_out;
    float* ws  = (float*)d_ws;      // needs 2400 floats = 9.6 KB

    pack_weights<<<dim3(10), dim3(256), 0, stream>>>(W1, b1, W2, ws);

    int B = in_sizes[1];  // t has B elements
    int grid = (B + 255) / 256;
    cvx_quad_kernel<<<dim3(grid), dim3(256), 0, stream>>>(z, t, ws, b2, out, B);
}

// Round 4
// 112.966 us; speedup vs baseline: 1.0511x; 1.0511x over previous
//
#include <hip/hip_runtime.h>

// CVXPolicy_Quadcopter: fused MLP (13->100 tanh ->12) + closed-form argmin via
// Lambert W. 1 element/thread; hidden units processed in PAIRS so the compiler
// can form v_pk_fma_f32 (packed fp32, 2 FMA / 2-cyc inst on CDNA):
//   - W1 repacked interleaved (w_j[k], w_j1[k]) with 2*log2(e) folded in, so
//     tanh uses exp2 directly (no mul) and there is no per-j horizontal add.
//   - W2 pairs accumulate into float2; one horizontal reduce at the end.
// Weight layout in ws (built by pack_weights):
//   region A: 50 rows x 32 floats: [pair(k=0)..pair(k=12), pair(b1'), pad x4]
//   region B (at +1600): 50 rows x 16 floats: [pair(m=0)..pair(m=5), pad x4]

constexpr int S = 12;   // z features
constexpr int H = 100;  // hidden
#define TWO_LOG2E 2.8853900817779268f

__device__ __forceinline__ float fast_rcp(float x) {
    return __builtin_amdgcn_rcpf(x);
}

// 2-wide fma: a*b+c elementwise; adjacent independent fmaf -> v_pk_fma_f32
__device__ __forceinline__ float2 fma2(float2 a, float2 b, float2 c) {
    return make_float2(fmaf(a.x, b.x, c.x), fmaf(a.y, b.y, c.y));
}

__global__ __launch_bounds__(256) void pack_weights(
    const float* __restrict__ W1, const float* __restrict__ b1,
    const float* __restrict__ W2, float* __restrict__ ws)
{
    int idx = blockIdx.x * 256 + threadIdx.x;
    if (idx < 1600) {                        // region A: jp = idx/32, s = idx%32
        int jp = idx >> 5, s = idx & 31;
        float v = 0.0f;
        if (s < 26) {
            int k = s >> 1, half = s & 1;
            v = W1[k * H + 2 * jp + half] * TWO_LOG2E;
        } else if (s < 28) {
            int half = s & 1;
            v = b1[2 * jp + half] * TWO_LOG2E;
        }
        ws[idx] = v;
    } else if (idx < 2400) {                 // region B: jp = r/16, s = r%16
        int r = idx - 1600;
        int jp = r >> 4, s = r & 15;
        float v = 0.0f;
        if (s < 12) {
            int m = s >> 1, half = s & 1;
            v = W2[(2 * jp + half) * S + 6 + m];
        }
        ws[idx] = v;
    }
}

__global__ __launch_bounds__(256) void cvx_quad_kernel(
    const float* __restrict__ z, const float* __restrict__ t,
    const float* __restrict__ ws, const float* __restrict__ b2,
    float* __restrict__ out, int B)
{
    int i = blockIdx.x * 256 + threadIdx.x;
    if (i >= B) return;

    // Load input row: [t, z0..z11]
    float inp[S + 1];
    inp[0] = t[i];
    const float4* zr = reinterpret_cast<const float4*>(z) + (size_t)i * 3;
    float4 a0 = zr[0], a1 = zr[1], a2 = zr[2];
    inp[1]  = a0.x; inp[2]  = a0.y; inp[3]  = a0.z; inp[4]  = a0.w;
    inp[5]  = a1.x; inp[6]  = a1.y; inp[7]  = a1.z; inp[8]  = a1.w;
    inp[9]  = a2.x; inp[10] = a2.y; inp[11] = a2.z; inp[12] = a2.w;

    // float2 accumulators for p[6..11] (pairwise over hidden units)
    float2 p[6];
    #pragma unroll
    for (int m = 0; m < 6; ++m) p[m] = make_float2(b2[6 + m], 0.0f);

    #pragma unroll 2
    for (int jp = 0; jp < H / 2; ++jp) {
        const float2* wrow = reinterpret_cast<const float2*>(ws + jp * 32);
        float2 acc = wrow[13];               // (b1'_j, b1'_j1), pre-scaled
        #pragma unroll
        for (int k = 0; k < S + 1; ++k) {
            float2 ik = make_float2(inp[k], inp[k]);
            acc = fma2(ik, wrow[k], acc);
        }
        // tanh(y) with acc = 2*log2e*y:  e = 2^acc = exp(2y)
        float eA = __builtin_amdgcn_exp2f(acc.x);
        float eB = __builtin_amdgcn_exp2f(acc.y);
        float thA = fmaf(-2.0f, fast_rcp(1.0f + eA), 1.0f);
        float thB = fmaf(-2.0f, fast_rcp(1.0f + eB), 1.0f);
        float2 th = make_float2(thA, thB);

        const float2* qrow = reinterpret_cast<const float2*>(ws + 1600 + jp * 16);
        #pragma unroll
        for (int m = 0; m < 6; ++m) {
            p[m] = fma2(th, qrow[m], p[m]);
        }
    }

    float p0 = p[0].x + p[0].y, p1 = p[1].x + p[1].y, p2 = p[2].x + p[2].y;
    float p3 = p[3].x + p[3].y, p4 = p[4].x + p[4].y, p5 = p[5].x + p[5].y;

    float c0 = 2.0f * (p0 + p1 + p2);  // / MASS, MASS = 0.5
    float c1 = p3, c2 = p4, c3 = p5;
    float x = fmaf(c0, c0, fmaf(c1, c1, fmaf(c2, c2, c3 * c3)));

    // Lambert W: solve w e^w = x, Newton from w0 = log(1+x)
    float w = __logf(1.0f + x);
    #pragma unroll
    for (int it = 0; it < 6; ++it) {
        float ew  = __expf(w);
        float num = fmaf(w, ew, -x);        // w*e^w - x
        float den = fmaf(ew, w, ew);        // e^w * (w + 1)
        w = w - num * fast_rcp(den);
    }

    float sc = -__expf(-0.5f * w);
    float4 o;
    o.x = c0 * sc;
    o.y = c1 * sc;
    o.z = c2 * sc;
    o.w = c3 * sc;
    reinterpret_cast<float4*>(out)[i] = o;
}

extern "C" void kernel_launch(void* const* d_in, const int* in_sizes, int n_in,
                              void* d_out, int out_size, void* d_ws, size_t ws_size,
                              hipStream_t stream) {
    const float* z  = (const float*)d_in[0];
    const float* t  = (const float*)d_in[1];
    const float* W1 = (const float*)d_in[2];
    const float* b1 = (const float*)d_in[3];
    const float* W2 = (const float*)d_in[4];
    const float* b2 = (const float*)d_in[5];
    float* out = (float*)d_out;
    float* ws  = (float*)d_ws;      // needs 2400 floats = 9.6 KB

    pack_weights<<<dim3(10), dim3(256), 0, stream>>>(W1, b1, W2, ws);

    int B = in_sizes[1];  // t has B elements
    int grid = (B + 255) / 256;
    cvx_quad_kernel<<<dim3(grid), dim3(256), 0, stream>>>(z, t, ws, b2, out, B);
}

// Round 5
// 105.891 us; speedup vs baseline: 1.1213x; 1.0668x over previous
//
#include <hip/hip_runtime.h>

// CVXPolicy_Quadcopter: fused MLP (13->100 tanh ->12) + closed-form argmin via
// Lambert W. 1 element/thread; hidden units in PAIRS mapped onto <2 x float>
// ext-vector ops so LLVM emits v_pk_fma_f32 (full-rate packed fp32) directly.
//   - W1 packed interleaved (w_j[k], w_j1[k]) scaled by 2*log2(e): tanh uses
//     exp2 with no multiply, no per-j horizontal add.
//   - tanh pair shares ONE v_rcp: 1/a,1/b = (b,a) * rcp(a*b).
//   - W2 pairs accumulate into vf2 lanes; one horizontal reduce at the end.
// ws layout (pack_weights):
//   region A: 50 rows x 32 floats: [pair(k=0)..pair(k=12), pair(b1'), pad x4]
//   region B (+1600): 50 rows x 16 floats: [pair(m=0)..pair(m=5), pad x4]

constexpr int S = 12;   // z features
constexpr int H = 100;  // hidden
#define TWO_LOG2E 2.8853900817779268f

typedef float vf2 __attribute__((ext_vector_type(2)));

__device__ __forceinline__ float fast_rcp(float x) {
    return __builtin_amdgcn_rcpf(x);
}

__global__ __launch_bounds__(256) void pack_weights(
    const float* __restrict__ W1, const float* __restrict__ b1,
    const float* __restrict__ W2, float* __restrict__ ws)
{
    int idx = blockIdx.x * 256 + threadIdx.x;
    if (idx < 1600) {                        // region A: jp = idx/32, s = idx%32
        int jp = idx >> 5, s = idx & 31;
        float v = 0.0f;
        if (s < 26) {
            int k = s >> 1, half = s & 1;
            v = W1[k * H + 2 * jp + half] * TWO_LOG2E;
        } else if (s < 28) {
            int half = s & 1;
            v = b1[2 * jp + half] * TWO_LOG2E;
        }
        ws[idx] = v;
    } else if (idx < 2400) {                 // region B: jp = r/16, s = r%16
        int r = idx - 1600;
        int jp = r >> 4, s = r & 15;
        float v = 0.0f;
        if (s < 12) {
            int m = s >> 1, half = s & 1;
            v = W2[(2 * jp + half) * S + 6 + m];
        }
        ws[idx] = v;
    }
}

__global__ __launch_bounds__(256) void cvx_quad_kernel(
    const float* __restrict__ z, const float* __restrict__ t,
    const float* __restrict__ ws, const float* __restrict__ b2,
    float* __restrict__ out, int B)
{
    int i = blockIdx.x * 256 + threadIdx.x;
    if (i >= B) return;

    // Load input row: [t, z0..z11]
    float inp[S + 1];
    inp[0] = t[i];
    const float4* zr = reinterpret_cast<const float4*>(z) + (size_t)i * 3;
    float4 a0 = zr[0], a1 = zr[1], a2 = zr[2];
    inp[1]  = a0.x; inp[2]  = a0.y; inp[3]  = a0.z; inp[4]  = a0.w;
    inp[5]  = a1.x; inp[6]  = a1.y; inp[7]  = a1.z; inp[8]  = a1.w;
    inp[9]  = a2.x; inp[10] = a2.y; inp[11] = a2.z; inp[12] = a2.w;

    // vf2 accumulators for p[6..11] (even/odd hidden-unit lanes)
    vf2 p[6];
    #pragma unroll
    for (int m = 0; m < 6; ++m) {
        float bm = b2[6 + m];
        p[m] = (vf2){bm, 0.0f};
    }

    #pragma unroll 2
    for (int jp = 0; jp < H / 2; ++jp) {
        const vf2* wrow = reinterpret_cast<const vf2*>(ws + jp * 32);
        vf2 acc = (vf2){inp[0], inp[0]} * wrow[0];        // v_pk_mul_f32
        #pragma unroll
        for (int k = 1; k < S + 1; ++k) {                 // 12x v_pk_fma_f32
            acc = __builtin_elementwise_fma((vf2){inp[k], inp[k]}, wrow[k], acc);
        }
        acc = acc + wrow[13];                             // bias' (pre-scaled)

        // tanh(y), acc = 2*log2e*y:  e = 2^acc = exp(2y); th = 1 - 2/(1+e)
        float eA = __builtin_amdgcn_exp2f(acc.x);
        float eB = __builtin_amdgcn_exp2f(acc.y);
        vf2 ab = (vf2){eA, eB} + (vf2){1.0f, 1.0f};       // {a, b}
        float r = fast_rcp(ab.x * ab.y);                  // one rcp per pair
        vf2 inv = (vf2){ab.y, ab.x} * (vf2){r, r};        // {1/a, 1/b}
        vf2 th = __builtin_elementwise_fma((vf2){-2.0f, -2.0f}, inv,
                                           (vf2){1.0f, 1.0f});

        const vf2* qrow = reinterpret_cast<const vf2*>(ws + 1600 + jp * 16);
        #pragma unroll
        for (int m = 0; m < 6; ++m) {                     // 6x v_pk_fma_f32
            p[m] = __builtin_elementwise_fma(th, qrow[m], p[m]);
        }
    }

    float p0 = p[0].x + p[0].y, p1 = p[1].x + p[1].y, p2 = p[2].x + p[2].y;
    float p3 = p[3].x + p[3].y, p4 = p[4].x + p[4].y, p5 = p[5].x + p[5].y;

    float c0 = 2.0f * (p0 + p1 + p2);  // / MASS, MASS = 0.5
    float c1 = p3, c2 = p4, c3 = p5;
    float x = fmaf(c0, c0, fmaf(c1, c1, fmaf(c2, c2, c3 * c3)));

    // Lambert W: solve w e^w = x, Newton from w0 = log(1+x)
    float w = __logf(1.0f + x);
    #pragma unroll
    for (int it = 0; it < 5; ++it) {
        float ew  = __expf(w);
        float num = fmaf(w, ew, -x);        // w*e^w - x
        float den = fmaf(ew, w, ew);        // e^w * (w + 1)
        w = w - num * fast_rcp(den);
    }

    float sc = -__expf(-0.5f * w);
    float4 o;
    o.x = c0 * sc;
    o.y = c1 * sc;
    o.z = c2 * sc;
    o.w = c3 * sc;
    reinterpret_cast<float4*>(out)[i] = o;
}

extern "C" void kernel_launch(void* const* d_in, const int* in_sizes, int n_in,
                              void* d_out, int out_size, void* d_ws, size_t ws_size,
                              hipStream_t stream) {
    const float* z  = (const float*)d_in[0];
    const float* t  = (const float*)d_in[1];
    const float* W1 = (const float*)d_in[2];
    const float* b1 = (const float*)d_in[3];
    const float* W2 = (const float*)d_in[4];
    const float* b2 = (const float*)d_in[5];
    float* out = (float*)d_out;
    float* ws  = (float*)d_ws;      // needs 2400 floats = 9.6 KB

    pack_weights<<<dim3(10), dim3(256), 0, stream>>>(W1, b1, W2, ws);

    int B = in_sizes[1];  // t has B elements
    int grid = (B + 255) / 256;
    cvx_quad_kernel<<<dim3(grid), dim3(256), 0, stream>>>(z, t, ws, b2, out, B);
}